// Round 1
// baseline (330.785 us; speedup 1.0000x reference)
//
#include <hip/hip_runtime.h>
#include <hip/hip_bf16.h>
#include <math.h>

#define BNEPS 1e-5f
#define BDIM_B 128
#define CDIM 512
#define SS 121
#define KK 9
#define MROWS (BDIM_B * SS)   // 15488

typedef unsigned short u16;
typedef __bf16 bf16x8 __attribute__((ext_vector_type(8)));
typedef float f32x4 __attribute__((ext_vector_type(4)));

__device__ __forceinline__ u16 f2bf(float f) {
    union { float f; unsigned int u; } v; v.f = f;
    unsigned int r = v.u + 0x7FFF + ((v.u >> 16) & 1);   // RNE
    return (u16)(r >> 16);
}
__device__ __forceinline__ float bf2f(u16 v) {
    union { unsigned int u; float f; } x; x.u = ((unsigned int)v) << 16; return x.f;
}

__device__ __forceinline__ void gld16(const u16* g, u16* l) {
    __builtin_amdgcn_global_load_lds(
        (const __attribute__((address_space(1))) void*)g,
        (__attribute__((address_space(3))) void*)l, 16, 0, 0);
}

__device__ __forceinline__ void wgbar() {
    asm volatile("" ::: "memory");
    __builtin_amdgcn_s_barrier();
    asm volatile("" ::: "memory");
}

// ---------------------------------------------------------------------------
// gemm256: 256x256 tile, BK=32, 4-slot LDS ring, counted-vmcnt deep pipeline.
// 512 thr = 8 waves (2M x 4N), per-wave C = 128x64 (8x4 frags), 1 block/CU.
// Ring schedule: tile t computes slot t&3 while tile t+3 stages into slot
// (t+3)&3 (previously freed at end of tile t-1). Invariant entering tile t:
// tiles t+1,t+2 in flight = 8 gld16/wave -> tile-end wait is vmcnt(8)
// (oldest 4 = tile t+1 landed), NEVER vmcnt(0) in the main loop.
// Prologue: stage t0,t1,t2 (12 loads), vmcnt(8) -> t0 landed.
// Epilogue tiles: vmcnt(4) -> vmcnt(0) -> none.
// XOR chunk-swizzle (source-side + read-side, same involution as the verified
// 128^2 kernel) keeps ds_read_b128 bank conflicts ~0.
// XCD swizzle: panel = (tt>>2)*8 + (blockIdx&7) -> one M-panel's 4 N-tiles on
// one XCD => A-panel fetched once per XCD (~4MB, L2-resident).
// MODE 1: BN+relu -> bf16, p-major remap Y[(m%121)*128 + m/121][n]
// MODE 2: BN+relu, reduce 128 rows (= one p per wave-half) -> bf16 out[p][n]
// ---------------------------------------------------------------------------
template<int MODE>
__global__ __launch_bounds__(512, 2)
void gemm256(const u16* __restrict__ A, const u16* __restrict__ Bw,
             const float* __restrict__ bias, const float* __restrict__ g,
             const float* __restrict__ bb, void* __restrict__ out,
             int Kd, int N, int Mvalid)
{
    __shared__ __align__(16) u16 As[4][256 * 32];
    __shared__ __align__(16) u16 Bs[4][256 * 32];

    const int tid  = threadIdx.x;
    const int lane = tid & 63;
    const int w    = tid >> 6;     // 0..7
    const int wm   = w >> 2;       // 0..1
    const int wn   = w & 3;        // 0..3

    const int MP   = (Mvalid + 255) >> 8;
    const int xcd  = blockIdx.x & 7;
    const int tt   = blockIdx.x >> 3;
    const int pnl  = (tt >> 2) * 8 + xcd;  // M-panel, same-XCD grouped
    const int bnid = tt & 3;
    if (pnl >= MP) return;
    const int bm = pnl * 256;
    const int bn = bnid * 256;

    // --- staging addressing (per-lane global, linear LDS dest) ---
    const int srow   = tid >> 2;                       // 0..127
    const int schunk = (tid & 3) ^ ((srow >> 1) & 3);  // source-side swizzle
    int ar0 = bm + srow;        if (ar0 >= Mvalid) ar0 = Mvalid - 1;  // ragged clamp
    int ar1 = bm + 128 + srow;  if (ar1 >= Mvalid) ar1 = Mvalid - 1;
    const u16* a0 = A  + (size_t)ar0 * Kd + schunk * 8;
    const u16* a1 = A  + (size_t)ar1 * Kd + schunk * 8;
    const u16* b0 = Bw + (size_t)(bn + srow) * Kd + schunk * 8;
    const u16* b1 = Bw + (size_t)(bn + 128 + srow) * Kd + schunk * 8;

#define STAGE_A(S_, T_) do { \
    gld16(a0 + (T_) * 32, &As[(S_)][(w * 16) * 32]); \
    gld16(a1 + (T_) * 32, &As[(S_)][(128 + w * 16) * 32]); \
} while (0)
#define STAGE_B(S_, T_) do { \
    gld16(b0 + (T_) * 32, &Bs[(S_)][(w * 16) * 32]); \
    gld16(b1 + (T_) * 32, &Bs[(S_)][(128 + w * 16) * 32]); \
} while (0)

    // --- fragment read addressing (read-side swizzle = same involution) ---
    const int frA = wm * 128 + (lane & 15);
    const int frB = wn * 64  + (lane & 15);
    const int rch = ((lane >> 4) ^ (((lane & 15) >> 1) & 3)) * 8;

    f32x4 acc[8][4] = {};

    const int NT = Kd >> 5;   // BK=32 tiles; NT >= 4 required (16 or 32 here)

    // --- prologue: 3 tiles staged, wait oldest tile ---
    STAGE_A(0, 0); STAGE_B(0, 0);
    asm volatile("" ::: "memory");
    STAGE_A(1, 1); STAGE_B(1, 1);
    asm volatile("" ::: "memory");
    STAGE_A(2, 2); STAGE_B(2, 2);
    asm volatile("s_waitcnt vmcnt(8)" ::: "memory");
    wgbar();

#define TILE(T_, DOSTAGE_, VMW_) do { \
    const int sl_ = (T_) & 3; \
    bf16x8 af_[8], bv_[4]; \
    _Pragma("unroll") \
    for (int i_ = 0; i_ < 4; ++i_) \
        af_[i_] = *(const bf16x8*)&As[sl_][(frA + i_ * 16) * 32 + rch]; \
    _Pragma("unroll") \
    for (int j_ = 0; j_ < 4; ++j_) \
        bv_[j_] = *(const bf16x8*)&Bs[sl_][(frB + j_ * 16) * 32 + rch]; \
    if (DOSTAGE_) STAGE_A(((T_) + 3) & 3, (T_) + 3); \
    wgbar(); \
    __builtin_amdgcn_s_setprio(1); \
    _Pragma("unroll") \
    for (int i_ = 0; i_ < 4; ++i_) \
        _Pragma("unroll") \
        for (int j_ = 0; j_ < 4; ++j_) \
            acc[i_][j_] = __builtin_amdgcn_mfma_f32_16x16x32_bf16(af_[i_], bv_[j_], acc[i_][j_], 0, 0, 0); \
    __builtin_amdgcn_s_setprio(0); \
    wgbar(); \
    _Pragma("unroll") \
    for (int i_ = 4; i_ < 8; ++i_) \
        af_[i_] = *(const bf16x8*)&As[sl_][(frA + i_ * 16) * 32 + rch]; \
    if (DOSTAGE_) STAGE_B(((T_) + 3) & 3, (T_) + 3); \
    wgbar(); \
    __builtin_amdgcn_s_setprio(1); \
    _Pragma("unroll") \
    for (int i_ = 4; i_ < 8; ++i_) \
        _Pragma("unroll") \
        for (int j_ = 0; j_ < 4; ++j_) \
            acc[i_][j_] = __builtin_amdgcn_mfma_f32_16x16x32_bf16(af_[i_], bv_[j_], acc[i_][j_], 0, 0, 0); \
    __builtin_amdgcn_s_setprio(0); \
    if ((VMW_) == 8)      asm volatile("s_waitcnt vmcnt(8)" ::: "memory"); \
    else if ((VMW_) == 4) asm volatile("s_waitcnt vmcnt(4)" ::: "memory"); \
    else if ((VMW_) == 0) asm volatile("s_waitcnt vmcnt(0)" ::: "memory"); \
    wgbar(); \
} while (0)

    for (int t = 0; t + 3 < NT; ++t)
        TILE(t, true, 8);
    TILE(NT - 3, false, 4);
    TILE(NT - 2, false, 0);
    TILE(NT - 1, false, -1);

#undef TILE
#undef STAGE_A
#undef STAGE_B

    const float inv = 1.0f / sqrtf(1.0f + BNEPS);

    if (MODE == 1) {
        u16* Y = (u16*)out;
        #pragma unroll
        for (int j = 0; j < 4; ++j) {
            int n = bn + wn * 64 + j * 16 + (lane & 15);
            float sc = g[n] * inv, bo = bias[n], bvv = bb[n];
            #pragma unroll
            for (int i = 0; i < 8; ++i) {
                int mb = bm + wm * 128 + i * 16 + (lane >> 4) * 4;
                #pragma unroll
                for (int r = 0; r < 4; ++r) {
                    int m = mb + r;
                    if (m < Mvalid) {
                        int b = m / 121, p = m - b * 121;
                        float v = (acc[i][j][r] + bo) * sc + bvv;
                        Y[(size_t)(p * 128 + b) * N + n] = f2bf(fmaxf(v, 0.0f));
                    }
                }
            }
        }
    } else {
        // wave-half wm owns rows [bm+wm*128, +128) = all b of p = 2*pnl+wm
        int p = pnl * 2 + wm;
        #pragma unroll
        for (int j = 0; j < 4; ++j) {
            int n = bn + wn * 64 + j * 16 + (lane & 15);
            float sc = g[n] * inv, bo = bias[n], bvv = bb[n];
            float s = 0.f;
            #pragma unroll
            for (int i = 0; i < 8; ++i)
                #pragma unroll
                for (int r = 0; r < 4; ++r)
                    s += fmaxf((acc[i][j][r] + bo) * sc + bvv, 0.0f);
            s += __shfl_xor(s, 16);   // combine the 4 row-quarters
            s += __shfl_xor(s, 32);
            if (p < SS && lane < 16)
                ((u16*)out)[(size_t)p * N + n] = f2bf(s);
        }
    }
}

// ---------------------------------------------------------------------------
// bf16 MFMA GEMM, 128x128 tile, BK=64 — retained for the tiny lo-path GEMMs
// (MODE 3: relu -> bf16 Yout[m*N+n];  MODE 4: sigmoid -> bf16 Yout[m*N+n])
// ---------------------------------------------------------------------------
template<int MODE, int SWIZ>
__global__ __launch_bounds__(256)
void gemm_mfma(const u16* __restrict__ A, const u16* __restrict__ Bw,
               const float* __restrict__ bias, const float* __restrict__ g,
               const float* __restrict__ bb, void* __restrict__ out,
               int Kd, int N, int NT)
{
    __shared__ __align__(16) u16 Als[2][128 * 32];
    __shared__ __align__(16) u16 Bls[2][128 * 32];

    const int tid  = threadIdx.x;
    const int lane = tid & 63;
    const int w    = tid >> 6;
    const int wm   = w >> 1, wn = w & 1;

    int bx, by;
    if (SWIZ) {
        int i = blockIdx.x;
        if (i < 960) {
            int xg = i & 7;
            int j  = i >> 3;
            bx = xg * 15 + (j >> 3);
            by = j & 7;
        } else { bx = 120; by = i - 960; }
    } else {
        bx = blockIdx.x / NT; by = blockIdx.x - bx * NT;
    }
    const int bm = bx * 128;
    const int bn = by * 128;

    f32x4 acc[4][4] = {};

    const int subrow = tid >> 2;
    const int kq     = tid & 3;
    const int gchunk = kq ^ ((subrow >> 1) & 3);
    const u16* Ab = A  + (size_t)(bm + subrow) * Kd + gchunk * 8;
    const u16* Bb = Bw + (size_t)(bn + subrow) * Kd + gchunk * 8;
    u16* Al0  = &Als[0][(w * 16) * 32];
    u16* Al1  = &Als[0][(w * 16 + 64) * 32];
    u16* Bl0  = &Bls[0][(w * 16) * 32];
    u16* Bl1  = &Bls[0][(w * 16 + 64) * 32];
    u16* Al0b = &Als[1][(w * 16) * 32];
    u16* Al1b = &Als[1][(w * 16 + 64) * 32];
    u16* Bl0b = &Bls[1][(w * 16) * 32];
    u16* Bl1b = &Bls[1][(w * 16 + 64) * 32];

    const int fa_row = wm * 64 + (lane & 15);
    const int fb_row = wn * 64 + (lane & 15);
    const int kofs   = (((lane >> 4) ^ (((lane & 15) >> 1) & 3))) * 8;

    for (int k0 = 0; k0 < Kd; k0 += 64) {
        __syncthreads();
        gld16(Ab + k0,                      Al0);
        gld16(Ab + (size_t)64 * Kd + k0,    Al1);
        gld16(Bb + k0,                      Bl0);
        gld16(Bb + (size_t)64 * Kd + k0,    Bl1);
        gld16(Ab + k0 + 32,                 Al0b);
        gld16(Ab + (size_t)64 * Kd + k0 + 32, Al1b);
        gld16(Bb + k0 + 32,                 Bl0b);
        gld16(Bb + (size_t)64 * Kd + k0 + 32, Bl1b);
        __syncthreads();

        #pragma unroll
        for (int hb = 0; hb < 2; ++hb) {
            const u16* Ah = &Als[hb][0];
            const u16* Bh = &Bls[hb][0];
            bf16x8 af[4], bfv[4];
            #pragma unroll
            for (int i = 0; i < 4; ++i)
                af[i] = *(const bf16x8*)&Ah[(fa_row + i * 16) * 32 + kofs];
            #pragma unroll
            for (int j = 0; j < 4; ++j)
                bfv[j] = *(const bf16x8*)&Bh[(fb_row + j * 16) * 32 + kofs];
            #pragma unroll
            for (int i = 0; i < 4; ++i)
                #pragma unroll
                for (int j = 0; j < 4; ++j)
                    acc[i][j] = __builtin_amdgcn_mfma_f32_16x16x32_bf16(af[i], bfv[j], acc[i][j], 0, 0, 0);
        }
    }

    const float inv = 1.0f / sqrtf(1.0f + BNEPS);

    if (MODE == 1) {
        u16* Y = (u16*)out;
        int dstrow[4][4];
        #pragma unroll
        for (int i = 0; i < 4; ++i) {
            int mb = bm + wm * 64 + i * 16 + (lane >> 4) * 4;
            #pragma unroll
            for (int r = 0; r < 4; ++r) {
                int m = mb + r;
                int b = m / 121, p = m - b * 121;
                dstrow[i][r] = p * 128 + b;
            }
        }
        #pragma unroll
        for (int j = 0; j < 4; ++j) {
            int n = bn + wn * 64 + j * 16 + (lane & 15);
            float sc = g[n] * inv, bo = bias[n], bv = bb[n];
            #pragma unroll
            for (int i = 0; i < 4; ++i)
                #pragma unroll
                for (int r = 0; r < 4; ++r) {
                    float v = (acc[i][j][r] + bo) * sc + bv;
                    v = fmaxf(v, 0.0f);
                    Y[(size_t)dstrow[i][r] * N + n] = f2bf(v);
                }
        }
    } else if (MODE == 2) {
        float ps[4];
        #pragma unroll
        for (int j = 0; j < 4; ++j) {
            int n = bn + wn * 64 + j * 16 + (lane & 15);
            float sc = g[n] * inv, bo = bias[n], bv = bb[n];
            float s = 0.f;
            #pragma unroll
            for (int i = 0; i < 4; ++i)
                #pragma unroll
                for (int r = 0; r < 4; ++r) {
                    float v = (acc[i][j][r] + bo) * sc + bv;
                    s += fmaxf(v, 0.0f);
                }
            ps[j] = s;
        }
        __syncthreads();
        float* red = (float*)Als;
        #pragma unroll
        for (int j = 0; j < 4; ++j)
            red[(wm * 4 + (lane >> 4)) * 128 + wn * 64 + j * 16 + (lane & 15)] = ps[j];
        __syncthreads();
        if (tid < 128) {
            float s = 0.f;
            #pragma unroll
            for (int r = 0; r < 8; ++r) s += red[r * 128 + tid];
            ((u16*)out)[(size_t)bx * N + bn + tid] = f2bf(s);
        }
    } else {
        u16* Y = (u16*)out;
        #pragma unroll
        for (int j = 0; j < 4; ++j) {
            int n = bn + wn * 64 + j * 16 + (lane & 15);
            float sc = g[n] * inv, bo = bias[n], bv = bb[n];
            #pragma unroll
            for (int i = 0; i < 4; ++i) {
                int mb = bm + wm * 64 + i * 16 + (lane >> 4) * 4;
                #pragma unroll
                for (int r = 0; r < 4; ++r) {
                    float v = (acc[i][j][r] + bo) * sc + bv;
                    if (MODE == 3) v = fmaxf(v, 0.0f);
                    else           v = 1.f / (1.f + expf(-v));
                    Y[(size_t)(mb + r) * N + n] = f2bf(v);
                }
            }
        }
    }
}

// ---------------------------------------------------------------------------
// prep combo: blocks [0,1024): x transpose -> Xb bf16
//             blocks [1024,..): weight casts + dct transpose + w_conv pad-cast
// ---------------------------------------------------------------------------
#define W1N (1024 * 512)
#define W2N (1024 * 1024)
#define L1N (1024 * 1024)
#define L2N (512 * 1024)
#define DCTN (512 * 121)
#define WCN (16 * 512)
#define PREP_ELEM (W1N + W2N + L1N + L2N + DCTN + WCN)
#define PREP_BLKS (1024 + (PREP_ELEM + 255) / 256)
__global__ void prep_combo(const float* __restrict__ x, u16* __restrict__ Xb,
                           const float* __restrict__ w1, const float* __restrict__ w2,
                           const float* __restrict__ l1, const float* __restrict__ l2,
                           const float* __restrict__ dct, const float* __restrict__ w_conv,
                           u16* __restrict__ o1, u16* __restrict__ o2,
                           u16* __restrict__ o3, u16* __restrict__ o4,
                           float* __restrict__ dctT, u16* __restrict__ wcb)
{
    __shared__ float t[64 * 121];
    if (blockIdx.x < 1024) {
        int b = blockIdx.x >> 3, c0 = (blockIdx.x & 7) * 64;
        for (int idx = threadIdx.x; idx < 64 * 121; idx += 256) {
            int c = idx / 121, p = idx - c * 121;
            t[idx] = x[((size_t)b * 512 + c0 + c) * 121 + p];
        }
        __syncthreads();
        for (int idx = threadIdx.x; idx < 121 * 64; idx += 256) {
            int p = idx >> 6, c = idx & 63;
            Xb[((size_t)(b * 121 + p)) * 512 + c0 + c] = f2bf(t[c * 121 + p]);
        }
        return;
    }
    int i = (blockIdx.x - 1024) * 256 + threadIdx.x;
    if (i < W1N) { o1[i] = f2bf(w1[i]); return; }
    i -= W1N;
    if (i < W2N) { o2[i] = f2bf(w2[i]); return; }
    i -= W2N;
    if (i < L1N) { o3[i] = f2bf(l1[i]); return; }
    i -= L1N;
    if (i < L2N) { o4[i] = f2bf(l2[i]); return; }
    i -= L2N;
    if (i < DCTN) {
        int p = i >> 9, c = i & 511;
        dctT[i] = dct[(size_t)c * 121 + p];
        return;
    }
    i -= DCTN;
    if (i < WCN) {
        int n = i >> 9, c = i & 511;
        wcb[i] = (n < 9) ? f2bf(w_conv[(size_t)n * 512 + c]) : (u16)0;
    }
}

// ---------------------------------------------------------------------------
// spatial MFMA GEMM + channel chain, one dispatch.
// ---------------------------------------------------------------------------
__global__ __launch_bounds__(256)
void spatial_ck_combo(const u16* __restrict__ Xb, const u16* __restrict__ Xt,
                      const u16* __restrict__ wcb, const float* __restrict__ b_conv,
                      const float* __restrict__ g_sp, const float* __restrict__ b_sp,
                      const float* __restrict__ dctT,
                      const float* __restrict__ fc1, const float* __restrict__ fc2,
                      const float* __restrict__ g_ch, const float* __restrict__ b_ch,
                      float* __restrict__ skb, float* __restrict__ skt,
                      float* __restrict__ ckbuf, float* __restrict__ ck_t)
{
    const float inv = 1.0f / sqrtf(1.0f + BNEPS);

    if (blockIdx.x < 122) {
        const int tid  = threadIdx.x;
        const int lane = tid & 63;
        const int w    = tid >> 6;
        const bool task = (blockIdx.x == 121);
        const u16* Arow = task ? Xt : Xb + (size_t)blockIdx.x * 128 * 512;

        const int fr = lane & 15;
        const int kq = lane >> 4;            // 0..3
        const int r0 = w * 32;               // wave's first row (local)

        f32x4 acc0 = {}, acc1 = {};
        const u16* a0p = Arow + (size_t)(r0 + fr) * 512 + kq * 8;
        const u16* a1p = Arow + (size_t)(r0 + 16 + fr) * 512 + kq * 8;
        const u16* bp  = wcb + (size_t)fr * 512 + kq * 8;
        #pragma unroll
        for (int k0 = 0; k0 < 512; k0 += 32) {
            bf16x8 a0 = *(const bf16x8*)(a0p + k0);
            bf16x8 a1 = *(const bf16x8*)(a1p + k0);
            bf16x8 b  = *(const bf16x8*)(bp + k0);
            acc0 = __builtin_amdgcn_mfma_f32_16x16x32_bf16(a0, b, acc0, 0, 0, 0);
            acc1 = __builtin_amdgcn_mfma_f32_16x16x32_bf16(a1, b, acc1, 0, 0, 0);
        }

        int n = lane & 15;
        if (n < 9) {
            float bo = b_conv[n];
            #pragma unroll
            for (int t = 0; t < 2; ++t) {
                f32x4 a = t ? acc1 : acc0;
                #pragma unroll
                for (int r = 0; r < 4; ++r) {
                    int mloc = r0 + t * 16 + (lane >> 4) * 4 + r;
                    if (!task) {
                        int m = blockIdx.x * 128 + mloc;
                        int p = m % 121;
                        float v = (a[r] + bo) * (g_sp[p] * inv) + b_sp[p];
                        skb[(size_t)m * 9 + n] = v;
                    } else if (mloc < 121) {
                        float v = (a[r] + bo) * (g_sp[mloc] * inv) + b_sp[mloc];
                        skt[(size_t)mloc * 9 + n] = v;
                    }
                }
            }
        }
        return;
    }

    __shared__ float yls[512];
    __shared__ float y2ls[32];
    const int g = blockIdx.x - 122;                    // 0..128
    const u16* src = (g < 128) ? Xb + (size_t)g * 121 * 512 : Xt;

    // stage 1: DCT pooling  y[c] = sum_p X[p,c]*dctT[p,c]
    for (int c = threadIdx.x; c < 512; c += 256) {
        float s = 0.f;
        for (int p = 0; p < SS; ++p)
            s += bf2f(src[(size_t)p * 512 + c]) * dctT[p * 512 + c];
        yls[c] = s;
    }
    __syncthreads();

    // stage 2: fc1 512->32 + relu (8-way k-split per output)
    {
        int o = threadIdx.x >> 3, kp = threadIdx.x & 7;
        const float* w = fc1 + (size_t)o * 512;
        float s = 0.f;
        for (int k = kp * 4; k < 512; k += 32) {
            float4 wv = *(const float4*)(w + k);
            float4 av = *(const float4*)(yls + k);
            s += wv.x * av.x + wv.y * av.y + wv.z * av.z + wv.w * av.w;
        }
        s += __shfl_xor(s, 1);
        s += __shfl_xor(s, 2);
        s += __shfl_xor(s, 4);
        if (kp == 0) y2ls[o] = fmaxf(s, 0.f);
    }
    __syncthreads();

    // stage 3: fc2 32->4608 + sigmoid + channel BN
    for (int o = threadIdx.x; o < CDIM * KK; o += 256) {
        const float* w = fc2 + (size_t)o * 32;
        float s = 0.f;
        #pragma unroll
        for (int k = 0; k < 32; ++k) s += y2ls[k] * w[k];
        s = 1.f / (1.f + expf(-s));
        int c = o / KK;
        s = s * (g_ch[c] * inv) + b_ch[c];
        if (g < 128) ckbuf[(size_t)g * CDIM * KK + o] = s;
        else         ck_t[o] = s;
    }
}

// ---------------------------------------------------------------------------
// final combo:
// blocks [0,1024): out0[b,c,p] = (1/9) sum_k unfold(x)[k]*PS[p,k]*CS[c,k] + x
// blocks [1024,..): tk write
// ---------------------------------------------------------------------------
#define TKN (CDIM * SS * KK)              // 557568
#define FIN_BLKS (1024 + (TKN + 255) / 256)
__global__ __launch_bounds__(256)
void final_combo(const float* __restrict__ x, const float* __restrict__ skb,
                 const float* __restrict__ sk_t, const float* __restrict__ ckbuf,
                 const float* __restrict__ ck_t, float* __restrict__ out0,
                 float* __restrict__ tk)
{
    __shared__ float PS[SS * KK];
    __shared__ float CS[64 * KK];
    __shared__ float XT[64 * SS];

    if (blockIdx.x >= 1024) {
        int idx = (blockIdx.x - 1024) * 256 + threadIdx.x;
        if (idx < TKN) {
            int k9 = idx % KK;
            int pc = idx / KK;
            int p = pc % SS, c = pc / SS;
            tk[idx] = sk_t[p * KK + k9] * ck_t[c * KK + k9];
        }
        return;
    }

    const int tid = threadIdx.x;
    const int b = blockIdx.x >> 3, c0 = (blockIdx.x & 7) * 64;

    const float* sp = skb + (size_t)b * SS * KK;
    for (int i = tid; i < SS * KK; i += 256) PS[i] = sp[i] * sk_t[i];
    const float* cp = ckbuf + ((size_t)b * CDIM + c0) * KK;
    const float* tp = ck_t + (size_t)c0 * KK;
    for (int i = tid; i < 64 * KK; i += 256) CS[i] = cp[i] * tp[i];
    const float* xp = x + ((size_t)b * CDIM + c0) * SS;
    for (int i = tid; i < 64 * SS; i += 256) XT[i] = xp[i];
    __syncthreads();

    float* op = out0 + ((size_t)b * CDIM + c0) * SS;
    for (int i = tid; i < 64 * SS; i += 256) {
        int c = i / SS, p = i - c * SS;
        int h = p / 11, w = p - h * 11;
        const float* xc = XT + c * SS;
        const float* ps = PS + p * KK;
        const float* cs = CS + c * KK;
        float acc = 0.f;
        #pragma unroll
        for (int di = 0; di < 3; ++di) {
            int hh = h + di - 1;
            bool hv = (unsigned)hh < 11u;
            #pragma unroll
            for (int dj = 0; dj < 3; ++dj) {
                int ww = w + dj - 1;
                int k = di * 3 + dj;
                float xv = (hv && (unsigned)ww < 11u) ? xc[hh * 11 + ww] : 0.f;
                acc += xv * ps[k] * cs[k];
            }
        }
        op[i] = acc * (1.0f / 9.0f) + xc[p];
    }
}

extern "C" void kernel_launch(void* const* d_in, const int* in_sizes, int n_in,
                              void* d_out, int out_size, void* d_ws, size_t ws_size,
                              hipStream_t stream)
{
    const float* x      = (const float*)d_in[0];
    const float* dct_w  = (const float*)d_in[1];
    const float* w_conv = (const float*)d_in[2];
    const float* b_conv = (const float*)d_in[3];
    const float* g_sp   = (const float*)d_in[4];
    const float* b_sp   = (const float*)d_in[5];
    const float* g_ch   = (const float*)d_in[6];
    const float* b_ch   = (const float*)d_in[7];
    const float* fc1    = (const float*)d_in[8];
    const float* fc2    = (const float*)d_in[9];
    const float* up_w1  = (const float*)d_in[10];
    const float* up_b1  = (const float*)d_in[11];
    const float* up_g1  = (const float*)d_in[12];
    const float* up_bb1 = (const float*)d_in[13];
    const float* up_w2  = (const float*)d_in[14];
    const float* up_b2  = (const float*)d_in[15];
    const float* up_g2  = (const float*)d_in[16];
    const float* up_bb2 = (const float*)d_in[17];
    const float* lo_w1  = (const float*)d_in[18];
    const float* lo_b1  = (const float*)d_in[19];
    const float* lo_g1  = (const float*)d_in[20];
    const float* lo_bb1 = (const float*)d_in[21];
    const float* lo_w2  = (const float*)d_in[22];
    const float* lo_b2  = (const float*)d_in[23];
    const float* lo_g2  = (const float*)d_in[24];
    const float* lo_bb2 = (const float*)d_in[25];

    float* out0 = (float*)d_out;                       // (B,C,11,11)
    float* tk   = out0 + (size_t)BDIM_B * CDIM * SS;   // (1,C,11,11,3,3)

    // workspace layout (bytes, 64B-aligned chunks)
    char* ws = (char*)d_ws;
    size_t off = 0;
    auto alloc = [&](size_t bytes) { void* p = ws + off; off += (bytes + 63) & ~(size_t)63; return p; };
    u16*   Xb      = (u16*)alloc((size_t)MROWS * 512 * 2);
    u16*   Y1      = (u16*)alloc((size_t)MROWS * 1024 * 2);
    u16*   w1b     = (u16*)alloc((size_t)W1N * 2);
    u16*   w2b     = (u16*)alloc((size_t)W2N * 2);
    u16*   lw1b    = (u16*)alloc((size_t)L1N * 2);
    u16*   lw2b    = (u16*)alloc((size_t)L2N * 2);
    u16*   asum_b  = (u16*)alloc((size_t)128 * 1024 * 2);   // rows 121..127 unwritten
    u16*   a3b     = (u16*)alloc((size_t)128 * 1024 * 2);
    u16*   ts_pc   = (u16*)alloc((size_t)128 * 512 * 2);    // task_s (p,c) bf16
    float* dctT    = (float*)alloc((size_t)SS * 512 * 4);
    u16*   wcb     = (u16*)alloc((size_t)WCN * 2);          // w_conv bf16 16x512 (pad)
    float* ckbuf   = (float*)alloc((size_t)BDIM_B * CDIM * KK * 4);
    float* skbuf   = (float*)alloc((size_t)BDIM_B * SS * KK * 4);
    float* ck_t    = (float*)alloc((size_t)CDIM * KK * 4);
    float* sk_t    = (float*)alloc((size_t)SS * KK * 4);

    // --- prep: x transpose + weight casts + dct transpose + w_conv pad ---
    hipLaunchKernelGGL(prep_combo, dim3(PREP_BLKS), dim3(256), 0, stream,
                       x, Xb, up_w1, up_w2, lo_w1, lo_w2, dct_w, w_conv,
                       w1b, w2b, lw1b, lw2b, dctT, wcb);

    // --- up path: two 256^2 deep-pipelined MFMA GEMMs (counted vmcnt) ---
    hipLaunchKernelGGL((gemm256<1>), dim3(256), dim3(512), 0, stream,
                       Xb, w1b, up_b1, up_g1, up_bb1, (void*)Y1, 512, 1024, MROWS);
    hipLaunchKernelGGL((gemm256<2>), dim3(256), dim3(512), 0, stream,
                       Y1, w2b, up_b2, up_g2, up_bb2, (void*)asum_b, 1024, 1024, MROWS);

    // --- lo path: MFMA GEMMs on padded M=128 (rows 121..127 garbage, unread) ---
    hipLaunchKernelGGL((gemm_mfma<3, 0>), dim3(8), dim3(256), 0, stream,
                       asum_b, lw1b, lo_b1, lo_g1, lo_bb1, (void*)a3b, 1024, 1024, 8);
    hipLaunchKernelGGL((gemm_mfma<4, 0>), dim3(4), dim3(256), 0, stream,
                       a3b, lw2b, lo_b2, lo_g2, lo_bb2, (void*)ts_pc, 1024, 512, 4);

    // --- spatial MFMA GEMM + channel chain, one dispatch ---
    hipLaunchKernelGGL(spatial_ck_combo, dim3(122 + 129), dim3(256), 0, stream,
                       Xb, ts_pc, wcb, b_conv, g_sp, b_sp,
                       dctT, fc1, fc2, g_ch, b_ch,
                       skbuf, sk_t, ckbuf, ck_t);

    // --- final fused + task-kernel write, one dispatch ---
    hipLaunchKernelGGL(final_combo, dim3(FIN_BLKS), dim3(256), 0, stream,
                       x, skbuf, sk_t, ckbuf, ck_t, out0, tk);
}